// Round 13
// baseline (245.097 us; speedup 1.0000x reference)
//
#include <hip/hip_runtime.h>

// SMPL body model forward.
// R12: dispatch-count attack. R11 falsified the transaction-bound theory for
// k_gemm (FETCH 41->12MB, WRITE 38->21MB, time unchanged at 47.5us, all pipes
// <17% busy) -- the pipeline is dominated by per-dispatch fixed costs, not
// inner loops. So: k_gemm+k_lbs2 fused into k_gl (identical grids; posed
// verts stay in LDS, 42MB vph round-trip eliminated), k_regm direct-write
// (no atomics -> no memset dispatch). 6 dispatches -> 4.

constexpr int N   = 512;
constexpr int V   = 6890;
constexpr int V3  = V * 3;        // 20670
constexpr int NJ  = 24;
constexpr int NB  = 10;
constexpr int NP  = 207;
constexpr int NK  = 95;
constexpr int KP  = 224;          // padded K for pose GEMM
constexpr int VP2 = 6912;         // V padded (108*64)

// workspace layout (float offsets)
constexpr size_t SCALE_OFF = (size_t)N * V3;                  // N
constexpr size_t SJ_OFF    = SCALE_OFF + N;                   // NB*72
constexpr size_t JT_OFF    = SJ_OFF + (size_t)NB * 72;        // 72
constexpr size_t J_OFF     = JT_OFF + 72;
constexpr size_t A_OFF     = J_OFF + (size_t)N * 72;
constexpr size_t BF_OFF    = A_OFF + (size_t)N * 288;         // bf16/fp16 region
// region (ushort offsets)
constexpr size_t APF_U     = 0;                               // apf_sw [N/16][7][64][8] bf16
constexpr int    BP_COLS   = 20736;                           // 108*192 col pad
constexpr size_t BP_U      = (size_t)N * KP;                  // bp_sw [1296][7][64][8] bf16
constexpr size_t RB_U      = BP_U + (size_t)BP_COLS * KP;     // reg fp16 [96][VP2]
constexpr size_t VB_U      = RB_U + (size_t)96 * VP2;         // verts fp16 [N][3][VP2]
constexpr size_t BF_END_U  = VB_U + (size_t)N * 3 * VP2;
constexpr size_t WT_OFF    = BF_OFF + (BF_END_U + 1) / 2;     // w16 fp16 [VP2][32]
constexpr size_t AN_OFF    = WT_OFF + (size_t)VP2 * 32 / 2;   // an16 fp16 [N][16][32]

// k_static section block counts
constexpr int NB_REGBF = (96 * VP2) / 256;   // 2592
constexpr int NB_BT    = BP_COLS / 64;       // 324
constexpr int NB_WT    = VP2 / 256;          // 27
constexpr int NB_PRE   = 72;
constexpr int NB_STATIC = NB_REGBF + NB_BT + NB_WT + NB_PRE;

typedef short s16x8 __attribute__((ext_vector_type(8)));
typedef _Float16 h16x8 __attribute__((ext_vector_type(8)));
typedef float f32x4 __attribute__((ext_vector_type(4)));

__device__ inline unsigned short f2bf(float f) {
    unsigned u = __float_as_uint(f);
    u += 0x7fffu + ((u >> 16) & 1u);   // round-to-nearest-even
    return (unsigned short)(u >> 16);
}

// ---------------------------------------------------------------------------
// k_static: sectioned batch-independent prep (regbf | bt | wt | pre).
__global__ __launch_bounds__(256) void k_static(const float* __restrict__ pdirs,
                                                const float* __restrict__ sd,
                                                const float* __restrict__ jreg,
                                                const float* __restrict__ vt,
                                                const float* __restrict__ lbsw,
                                                const float* __restrict__ b25,
                                                const float* __restrict__ face,
                                                unsigned short* __restrict__ bp,
                                                _Float16* __restrict__ rb,
                                                _Float16* __restrict__ w16,
                                                float* __restrict__ ws) {
    __shared__ unsigned short smem[KP * 64];     // 28 KB, reused per section
    int b = blockIdx.x;
    int tid = threadIdx.x;

    if (b < NB_REGBF) {
        int t = b * 256 + tid;
        int k = t / VP2, v = t - k * VP2;
        float val = 0.f;
        if (v < V && k < NK)
            val = (k < 25) ? b25[(size_t)k * V + v] : face[(size_t)(k - 25) * V + v];
        rb[t] = (_Float16)val;
        return;
    }
    b -= NB_REGBF;
    if (b < NB_BT) {
        // stage [k][cl] then emit FRAGMENT layout bp[(ctg*7+kk)*64+lane][8]
        int c0 = b * 64;
#pragma unroll 4
        for (int i = 0; i < 56; ++i) {
            int e = tid + 256 * i;
            int k = e >> 6, cl = e & 63;
            int col = c0 + cl;
            float v = 0.f;
            if (col < V3) {
                if (k < NP) v = pdirs[(size_t)k * V3 + col];
                else if (k < NP + NB) v = sd[(size_t)(k - NP) * V3 + col];
            }
            smem[k * 64 + cl] = f2bf(v);
        }
        __syncthreads();
        for (int i = 0; i < 7; ++i) {
            int u = tid + 256 * i;                // 0..1791
            int ct_loc = u / 448;
            int rem = u - ct_loc * 448;
            int kk = rem >> 6, lane = rem & 63;
            int m = lane & 15, q = lane >> 4;
            s16x8 r;
#pragma unroll
            for (int j = 0; j < 8; ++j)
                r[j] = (short)smem[(kk * 32 + q * 8 + j) * 64 + ct_loc * 16 + m];
            size_t ctg = (size_t)(c0 >> 4) + ct_loc;
            *reinterpret_cast<s16x8*>(&bp[((ctg * 7 + kk) * 64 + lane) * 8]) = r;
        }
        return;
    }
    b -= NB_BT;
    if (b < NB_WT) {
        // w16[v][k=j] fp16, A-operand layout for the T-MFMA
        float* t = reinterpret_cast<float*>(smem);
        int v0 = b * 256;
        for (int e = tid; e < 256 * 24; e += 256) {
            int g = v0 * 24 + e;
            float val = (g < V * NJ) ? lbsw[g] : 0.f;
            int vv = e / 24, j = e - vv * 24;
            t[vv * 25 + j] = val;
        }
        __syncthreads();
        _Float16* dst = w16 + (size_t)(v0 + tid) * 32;
#pragma unroll
        for (int j = 0; j < 32; ++j)
            dst[j] = (j < NJ) ? (_Float16)t[tid * 25 + j] : (_Float16)0.f;
        return;
    }
    b -= NB_WT;
    // pre: SJ / Jt, block per jc, shuffle reduce
    int jc = b;
    int j = jc / 3, c = jc % 3;
    float acc[NB + 1];
#pragma unroll
    for (int t = 0; t <= NB; ++t) acc[t] = 0.f;
    for (int v = tid; v < V; v += 256) {
        float w = jreg[(size_t)j * V + v];
        int col = v * 3 + c;
#pragma unroll
        for (int k = 0; k < NB; ++k) acc[k] += w * sd[(size_t)k * V3 + col];
        acc[NB] += w * vt[col];
    }
    float* red = reinterpret_cast<float*>(smem);
    int lane = tid & 63, w64 = tid >> 6;
#pragma unroll
    for (int t = 0; t <= NB; ++t) {
        float a = acc[t];
#pragma unroll
        for (int s = 1; s < 64; s <<= 1) a += __shfl_xor(a, s, 64);
        if (lane == 0) red[w64 * 16 + t] = a;
    }
    __syncthreads();
    if (tid <= NB) {
        float s = red[tid] + red[16 + tid] + red[32 + tid] + red[48 + tid];
        if (tid < NB) ws[SJ_OFF + (size_t)tid * 72 + jc] = s;
        else          ws[JT_OFF + jc] = s;
    }
}

// ---------------------------------------------------------------------------
// k_head: scale + J + apf(fragment layout) + FK + an16. One wave per n.
__global__ __launch_bounds__(64) void k_head(const float* __restrict__ pose,
                                             const float* __restrict__ betas,
                                             const float* __restrict__ vt,
                                             const float* __restrict__ sd,
                                             float* __restrict__ ws,
                                             unsigned short* __restrict__ apf,
                                             _Float16* __restrict__ an16) {
    int n = blockIdx.x;
    int tid = threadIdx.x;
    __shared__ float sval[4];
    __shared__ float Jl[NJ * 3];
    __shared__ float G[NJ * 12];
    __shared__ unsigned short pfsh[KP];

    const int idx4[4] = {2802 * 3 + 1, 6262 * 3 + 1, 2237 * 3 + 1, 6728 * 3 + 1};
    if (tid < 4) {
        float a = vt[idx4[tid]];
#pragma unroll
        for (int k = 0; k < NB; ++k)
            a += betas[n * NB + k] * sd[(size_t)k * V3 + idx4[tid]];
        sval[tid] = a;
    }
    __syncthreads();
    float scale = 1.66f / (sval[0] + sval[1] - sval[2] - sval[3]);
    if (tid == 0) ws[SCALE_OFF + n] = scale;

    for (int k = tid; k < KP; k += 64) {
        float v = 0.f;
        if (k < NP) {
            v = pose[(size_t)n * 216 + 9 + k];
            int km = k % 9;
            if (km == 0 || km == 4 || km == 8) v -= 1.f;
        } else if (k < NP + NB) {
            v = scale * betas[n * NB + (k - NP)];
        }
        pfsh[k] = f2bf(v);
    }
    for (int e = tid; e < 72; e += 64) {
        float a = ws[JT_OFF + e];
#pragma unroll
        for (int k = 0; k < NB; ++k)
            a += betas[n * NB + k] * ws[SJ_OFF + (size_t)k * 72 + e];
        Jl[e] = scale * a;
    }
    __syncthreads();
    // apf fragment layout: [(n/16)*7+kk][lane=q*16+(n&15)][8]
    if (tid < 28) {
        int kk = tid >> 2, q = tid & 3;
        s16x8 r;
#pragma unroll
        for (int j = 0; j < 8; ++j) r[j] = (short)pfsh[kk * 32 + q * 8 + j];
        size_t off = ((size_t)(n >> 4) * 7 + kk) * 64 + q * 16 + (n & 15);
        *reinterpret_cast<s16x8*>(&apf[off * 8]) = r;
    }

    const int par[NJ] = {0,0,0,0,1,2,3,4,5,6,7,8,9,9,9,12,13,14,16,17,18,19,20,21};
    if (tid < 12) {
        int r = tid >> 2, c = tid & 3;
        G[tid] = (c < 3) ? pose[(size_t)n * 216 + r * 3 + c] : Jl[r];
    }
    __syncthreads();
    for (int i = 1; i < NJ; ++i) {
        int p = par[i];
        if (tid < 12) {
            int r = tid >> 2, c = tid & 3;
            const float* gp = &G[p * 12 + r * 4];
            float v;
            if (c < 3) {
                const float* Ri = pose + (size_t)n * 216 + i * 9;
                v = gp[0] * Ri[0 * 3 + c] + gp[1] * Ri[1 * 3 + c] + gp[2] * Ri[2 * 3 + c];
            } else {
                float t0 = Jl[i * 3 + 0] - Jl[p * 3 + 0];
                float t1 = Jl[i * 3 + 1] - Jl[p * 3 + 1];
                float t2 = Jl[i * 3 + 2] - Jl[p * 3 + 2];
                v = gp[0] * t0 + gp[1] * t1 + gp[2] * t2 + gp[3];
            }
            G[i * 12 + tid] = v;
        }
        __syncthreads();
    }
    // an16[n][col(16)][k=j(32)]
    for (int e = tid; e < 512; e += 64) {
        int col = e >> 5, j = e & 31;
        float v = 0.f;
        if (col < 12 && j < NJ) {
            int r = col >> 2, c = col & 3;
            if (c < 3) v = G[j * 12 + r * 4 + c];
            else {
                const float* g = &G[j * 12 + r * 4];
                v = g[3] - (g[0] * Jl[j * 3 + 0] + g[1] * Jl[j * 3 + 1] + g[2] * Jl[j * 3 + 2]);
            }
        }
        an16[(size_t)n * 512 + e] = (_Float16)v;
    }
}

// ---------------------------------------------------------------------------
// k_gl: fused pose-GEMM + LBS. Block = 64 v x 64 n (grids were identical).
// Stage 1: MFMA GEMM (fragment-layout operands), epilogue -> LDS sm (fp16).
// Stage 2: T = W@A via MFMA (4 n per barrier-pair), apply against LDS-resident
// posed verts, write vb (planar fp16) directly. vph never touches global.
__global__ __launch_bounds__(256) void k_gl(const unsigned short* __restrict__ apf,
                                            const unsigned short* __restrict__ bp,
                                            const float* __restrict__ vt,
                                            const float* __restrict__ ws,
                                            const _Float16* __restrict__ w16,
                                            const _Float16* __restrict__ an16,
                                            const float* __restrict__ trans,
                                            _Float16* __restrict__ vb) {
    int tid = threadIdx.x;
    int lane = tid & 63, w = tid >> 6;
    int m = lane & 15, q = lane >> 4;
    int cb = blockIdx.x;                 // 0..107  (64-v tile)
    int nb = blockIdx.y;                 // 0..7    (64-n tile)
    int nt = nb * 4 + w;

    __shared__ __align__(16) _Float16 sm[3][64][72];   // 27.6 KB posed verts
    __shared__ float smT[4][4][16][20];                // 20.5 KB T staging
    __shared__ float svt[192];
    __shared__ float ssc[64];
    __shared__ float strans[192];
    if (tid < 192) {
        int col = cb * 192 + tid;
        svt[tid] = (col < V3) ? vt[col] : 0.f;
        strans[tid] = trans[nb * 192 + tid];
    }
    if (tid < 64) ssc[tid] = ws[SCALE_OFF + nb * 64 + tid];

    // ---- stage 1: pose GEMM
    const unsigned short* abase = apf + (size_t)nt * 7 * 512 + lane * 8;
    const unsigned short* bbase = bp + (size_t)cb * 12 * 7 * 512 + lane * 8;

    f32x4 acc[12];
#pragma unroll
    for (int ct = 0; ct < 12; ++ct) acc[ct] = (f32x4){0.f, 0.f, 0.f, 0.f};

#pragma unroll
    for (int kk = 0; kk < 7; ++kk) {
        s16x8 a = *reinterpret_cast<const s16x8*>(abase + kk * 512);
#pragma unroll
        for (int ct = 0; ct < 12; ++ct) {
            s16x8 bfr = *reinterpret_cast<const s16x8*>(bbase + (ct * 7 + kk) * 512);
            acc[ct] = __builtin_amdgcn_mfma_f32_16x16x32_bf16(a, bfr, acc[ct], 0, 0, 0);
        }
    }
    __syncthreads();          // svt/ssc ready
#pragma unroll
    for (int ct = 0; ct < 12; ++ct) {
        int col_loc = ct * 16 + m;
        int v_loc = col_loc / 3;
        int c = col_loc - 3 * v_loc;
        float vtc = svt[col_loc];
#pragma unroll
        for (int r = 0; r < 4; ++r) {
            int n_loc = w * 16 + q * 4 + r;
            sm[c][n_loc][v_loc] = (_Float16)(acc[ct][r] + ssc[n_loc] * vtc);
        }
    }

    // ---- stage 2: LBS (T via MFMA, apply from LDS)
    h16x8 wf = *reinterpret_cast<const h16x8*>(
        &w16[(size_t)(cb * 64 + w * 16 + m) * 32 + q * 8]);
    int vloc = tid & 63, cc = tid >> 6;      // cc==3 idle in apply
    size_t vglob = (size_t)cb * 64 + vloc;
    __syncthreads();                          // sm complete

    for (int it = 0; it < 16; ++it) {
        int na = nb * 64 + it * 4;
#pragma unroll
        for (int which = 0; which < 4; ++which) {
            h16x8 bf = *reinterpret_cast<const h16x8*>(
                &an16[(size_t)(na + which) * 512 + m * 32 + q * 8]);
            f32x4 at = {0.f, 0.f, 0.f, 0.f};
            at = __builtin_amdgcn_mfma_f32_16x16x32_f16(wf, bf, at, 0, 0, 0);
#pragma unroll
            for (int r = 0; r < 4; ++r)
                smT[which][w][q * 4 + r][m] = at[r];
        }
        __syncthreads();
        if (cc < 3) {
#pragma unroll
            for (int which = 0; which < 4; ++which) {
                int nl = it * 4 + which;
                float4 T = *reinterpret_cast<const float4*>(
                    &smT[which][vloc >> 4][vloc & 15][cc * 4]);
                float px = (float)sm[0][nl][vloc];
                float py = (float)sm[1][nl][vloc];
                float pz = (float)sm[2][nl][vloc];
                float r = T.x * px + T.y * py + T.z * pz + T.w + strans[nl * 3 + cc];
                vb[(size_t)(nb * 64 + nl) * 3 * VP2 + (size_t)cc * VP2 + vglob] =
                    (_Float16)r;
            }
        }
        __syncthreads();
    }
}

// ---------------------------------------------------------------------------
// k_regm v3: one block per nc-tile, full K per block (4-wave split), LDS
// combine, DIRECT stores (no atomics, no memset).
__global__ __launch_bounds__(256) void k_regm(const _Float16* __restrict__ rb,
                                              const _Float16* __restrict__ vb,
                                              float* __restrict__ out) {
    int tid = threadIdx.x;
    int lane = tid & 63, w = tid >> 6;
    int m = lane & 15, q = lane >> 4;
    int nct = blockIdx.x;                    // 0..95

    const _Float16* brow = vb + (size_t)(nct * 16 + m) * VP2 + q * 8;
    const _Float16* abase = rb + (size_t)m * VP2 + q * 8;
    int vstart = w * (VP2 / 4);              // 54 steps of 32 per wave

    f32x4 acc[6];
#pragma unroll
    for (int kt = 0; kt < 6; ++kt) acc[kt] = (f32x4){0.f, 0.f, 0.f, 0.f};

    for (int s = 0; s < 54; ++s) {
        int off = vstart + s * 32;
        h16x8 b = *reinterpret_cast<const h16x8*>(brow + off);
#pragma unroll
        for (int kt = 0; kt < 6; ++kt) {
            h16x8 a = *reinterpret_cast<const h16x8*>(abase + (size_t)kt * 16 * VP2 + off);
            acc[kt] = __builtin_amdgcn_mfma_f32_16x16x32_f16(a, b, acc[kt], 0, 0, 0);
        }
    }
    __shared__ float sm[4][6][256];          // 24 KB
#pragma unroll
    for (int kt = 0; kt < 6; ++kt)
#pragma unroll
        for (int r = 0; r < 4; ++r)
            sm[w][kt][(q * 4 + r) * 16 + m] = acc[kt][r];
    __syncthreads();
    for (int e = tid; e < 6 * 256; e += 256) {
        int kt = e >> 8, i = e & 255;
        float s = sm[0][kt][i] + sm[1][kt][i] + sm[2][kt][i] + sm[3][kt][i];
        int k = kt * 16 + (i >> 4);
        int nc = nct * 16 + (i & 15);
        if (k < NK) {
            int n = nc / 3, c = nc - n * 3;
            out[(size_t)n * (NK * 3) + k * 3 + c] = s;
        }
    }
}

// ---------------------------------------------------------------------------
extern "C" void kernel_launch(void* const* d_in, const int* in_sizes, int n_in,
                              void* d_out, int out_size, void* d_ws, size_t ws_size,
                              hipStream_t stream) {
    const float* pose  = (const float*)d_in[0];
    const float* betas = (const float*)d_in[1];
    const float* trans = (const float*)d_in[2];
    const float* vt    = (const float*)d_in[3];
    const float* sd    = (const float*)d_in[4];
    const float* jreg  = (const float*)d_in[5];
    const float* pdirs = (const float*)d_in[6];
    const float* lbsw  = (const float*)d_in[7];
    const float* b25   = (const float*)d_in[8];
    const float* face  = (const float*)d_in[9];
    float* ws  = (float*)d_ws;
    float* out = (float*)d_out;
    unsigned short* bf  = (unsigned short*)(ws + BF_OFF);
    unsigned short* apf = bf + APF_U;
    unsigned short* bp  = bf + BP_U;
    _Float16* rb  = (_Float16*)(bf + RB_U);
    _Float16* vb  = (_Float16*)(bf + VB_U);
    _Float16* w16 = (_Float16*)(ws + WT_OFF);
    _Float16* an16 = (_Float16*)(ws + AN_OFF);

    k_static<<<NB_STATIC, 256, 0, stream>>>(pdirs, sd, jreg, vt, lbsw, b25, face,
                                            bp, rb, w16, ws);
    k_head  <<<N, 64, 0, stream>>>(pose, betas, vt, sd, ws, apf, an16);
    k_gl    <<<dim3(108, 8), 256, 0, stream>>>(apf, bp, vt, ws, w16, an16, trans, vb);
    k_regm  <<<96, 256, 0, stream>>>(rb, vb, out);
}

// Round 14
// 195.608 us; speedup vs baseline: 1.2530x; 1.2530x over previous
//
#include <hip/hip_runtime.h>

// SMPL body model forward.
// R13: k_regm parallelism restored. R12's direct-write k_regm (96 blocks,
// occupancy 4%) was a latency-bound drip-feed at 78us. Back to v-split +
// atomicAdd, now 6-way: grid (96 x 6) = 576 blocks = ~9 waves/CU. memset
// restored (measured ~2us through R11). k_gl fusion kept (that gain was real).

constexpr int N   = 512;
constexpr int V   = 6890;
constexpr int V3  = V * 3;        // 20670
constexpr int NJ  = 24;
constexpr int NB  = 10;
constexpr int NP  = 207;
constexpr int NK  = 95;
constexpr int KP  = 224;          // padded K for pose GEMM
constexpr int VP2 = 6912;         // V padded (108*64)

// workspace layout (float offsets)
constexpr size_t SCALE_OFF = (size_t)N * V3;                  // N
constexpr size_t SJ_OFF    = SCALE_OFF + N;                   // NB*72
constexpr size_t JT_OFF    = SJ_OFF + (size_t)NB * 72;        // 72
constexpr size_t J_OFF     = JT_OFF + 72;
constexpr size_t A_OFF     = J_OFF + (size_t)N * 72;
constexpr size_t BF_OFF    = A_OFF + (size_t)N * 288;         // bf16/fp16 region
// region (ushort offsets)
constexpr size_t APF_U     = 0;                               // apf_sw [N/16][7][64][8] bf16
constexpr int    BP_COLS   = 20736;                           // 108*192 col pad
constexpr size_t BP_U      = (size_t)N * KP;                  // bp_sw [1296][7][64][8] bf16
constexpr size_t RB_U      = BP_U + (size_t)BP_COLS * KP;     // reg fp16 [96][VP2]
constexpr size_t VB_U      = RB_U + (size_t)96 * VP2;         // verts fp16 [N][3][VP2]
constexpr size_t BF_END_U  = VB_U + (size_t)N * 3 * VP2;
constexpr size_t WT_OFF    = BF_OFF + (BF_END_U + 1) / 2;     // w16 fp16 [VP2][32]
constexpr size_t AN_OFF    = WT_OFF + (size_t)VP2 * 32 / 2;   // an16 fp16 [N][16][32]

// k_static section block counts
constexpr int NB_REGBF = (96 * VP2) / 256;   // 2592
constexpr int NB_BT    = BP_COLS / 64;       // 324
constexpr int NB_WT    = VP2 / 256;          // 27
constexpr int NB_PRE   = 72;
constexpr int NB_STATIC = NB_REGBF + NB_BT + NB_WT + NB_PRE;

typedef short s16x8 __attribute__((ext_vector_type(8)));
typedef _Float16 h16x8 __attribute__((ext_vector_type(8)));
typedef float f32x4 __attribute__((ext_vector_type(4)));

__device__ inline unsigned short f2bf(float f) {
    unsigned u = __float_as_uint(f);
    u += 0x7fffu + ((u >> 16) & 1u);   // round-to-nearest-even
    return (unsigned short)(u >> 16);
}

// ---------------------------------------------------------------------------
// k_static: sectioned batch-independent prep (regbf | bt | wt | pre).
__global__ __launch_bounds__(256) void k_static(const float* __restrict__ pdirs,
                                                const float* __restrict__ sd,
                                                const float* __restrict__ jreg,
                                                const float* __restrict__ vt,
                                                const float* __restrict__ lbsw,
                                                const float* __restrict__ b25,
                                                const float* __restrict__ face,
                                                unsigned short* __restrict__ bp,
                                                _Float16* __restrict__ rb,
                                                _Float16* __restrict__ w16,
                                                float* __restrict__ ws) {
    __shared__ unsigned short smem[KP * 64];     // 28 KB, reused per section
    int b = blockIdx.x;
    int tid = threadIdx.x;

    if (b < NB_REGBF) {
        int t = b * 256 + tid;
        int k = t / VP2, v = t - k * VP2;
        float val = 0.f;
        if (v < V && k < NK)
            val = (k < 25) ? b25[(size_t)k * V + v] : face[(size_t)(k - 25) * V + v];
        rb[t] = (_Float16)val;
        return;
    }
    b -= NB_REGBF;
    if (b < NB_BT) {
        // stage [k][cl] then emit FRAGMENT layout bp[(ctg*7+kk)*64+lane][8]
        int c0 = b * 64;
#pragma unroll 4
        for (int i = 0; i < 56; ++i) {
            int e = tid + 256 * i;
            int k = e >> 6, cl = e & 63;
            int col = c0 + cl;
            float v = 0.f;
            if (col < V3) {
                if (k < NP) v = pdirs[(size_t)k * V3 + col];
                else if (k < NP + NB) v = sd[(size_t)(k - NP) * V3 + col];
            }
            smem[k * 64 + cl] = f2bf(v);
        }
        __syncthreads();
        for (int i = 0; i < 7; ++i) {
            int u = tid + 256 * i;                // 0..1791
            int ct_loc = u / 448;
            int rem = u - ct_loc * 448;
            int kk = rem >> 6, lane = rem & 63;
            int m = lane & 15, q = lane >> 4;
            s16x8 r;
#pragma unroll
            for (int j = 0; j < 8; ++j)
                r[j] = (short)smem[(kk * 32 + q * 8 + j) * 64 + ct_loc * 16 + m];
            size_t ctg = (size_t)(c0 >> 4) + ct_loc;
            *reinterpret_cast<s16x8*>(&bp[((ctg * 7 + kk) * 64 + lane) * 8]) = r;
        }
        return;
    }
    b -= NB_BT;
    if (b < NB_WT) {
        // w16[v][k=j] fp16, A-operand layout for the T-MFMA
        float* t = reinterpret_cast<float*>(smem);
        int v0 = b * 256;
        for (int e = tid; e < 256 * 24; e += 256) {
            int g = v0 * 24 + e;
            float val = (g < V * NJ) ? lbsw[g] : 0.f;
            int vv = e / 24, j = e - vv * 24;
            t[vv * 25 + j] = val;
        }
        __syncthreads();
        _Float16* dst = w16 + (size_t)(v0 + tid) * 32;
#pragma unroll
        for (int j = 0; j < 32; ++j)
            dst[j] = (j < NJ) ? (_Float16)t[tid * 25 + j] : (_Float16)0.f;
        return;
    }
    b -= NB_WT;
    // pre: SJ / Jt, block per jc, shuffle reduce
    int jc = b;
    int j = jc / 3, c = jc % 3;
    float acc[NB + 1];
#pragma unroll
    for (int t = 0; t <= NB; ++t) acc[t] = 0.f;
    for (int v = tid; v < V; v += 256) {
        float w = jreg[(size_t)j * V + v];
        int col = v * 3 + c;
#pragma unroll
        for (int k = 0; k < NB; ++k) acc[k] += w * sd[(size_t)k * V3 + col];
        acc[NB] += w * vt[col];
    }
    float* red = reinterpret_cast<float*>(smem);
    int lane = tid & 63, w64 = tid >> 6;
#pragma unroll
    for (int t = 0; t <= NB; ++t) {
        float a = acc[t];
#pragma unroll
        for (int s = 1; s < 64; s <<= 1) a += __shfl_xor(a, s, 64);
        if (lane == 0) red[w64 * 16 + t] = a;
    }
    __syncthreads();
    if (tid <= NB) {
        float s = red[tid] + red[16 + tid] + red[32 + tid] + red[48 + tid];
        if (tid < NB) ws[SJ_OFF + (size_t)tid * 72 + jc] = s;
        else          ws[JT_OFF + jc] = s;
    }
}

// ---------------------------------------------------------------------------
// k_head: scale + J + apf(fragment layout) + FK + an16. One wave per n.
__global__ __launch_bounds__(64) void k_head(const float* __restrict__ pose,
                                             const float* __restrict__ betas,
                                             const float* __restrict__ vt,
                                             const float* __restrict__ sd,
                                             float* __restrict__ ws,
                                             unsigned short* __restrict__ apf,
                                             _Float16* __restrict__ an16) {
    int n = blockIdx.x;
    int tid = threadIdx.x;
    __shared__ float sval[4];
    __shared__ float Jl[NJ * 3];
    __shared__ float G[NJ * 12];
    __shared__ unsigned short pfsh[KP];

    const int idx4[4] = {2802 * 3 + 1, 6262 * 3 + 1, 2237 * 3 + 1, 6728 * 3 + 1};
    if (tid < 4) {
        float a = vt[idx4[tid]];
#pragma unroll
        for (int k = 0; k < NB; ++k)
            a += betas[n * NB + k] * sd[(size_t)k * V3 + idx4[tid]];
        sval[tid] = a;
    }
    __syncthreads();
    float scale = 1.66f / (sval[0] + sval[1] - sval[2] - sval[3]);
    if (tid == 0) ws[SCALE_OFF + n] = scale;

    for (int k = tid; k < KP; k += 64) {
        float v = 0.f;
        if (k < NP) {
            v = pose[(size_t)n * 216 + 9 + k];
            int km = k % 9;
            if (km == 0 || km == 4 || km == 8) v -= 1.f;
        } else if (k < NP + NB) {
            v = scale * betas[n * NB + (k - NP)];
        }
        pfsh[k] = f2bf(v);
    }
    for (int e = tid; e < 72; e += 64) {
        float a = ws[JT_OFF + e];
#pragma unroll
        for (int k = 0; k < NB; ++k)
            a += betas[n * NB + k] * ws[SJ_OFF + (size_t)k * 72 + e];
        Jl[e] = scale * a;
    }
    __syncthreads();
    // apf fragment layout: [(n/16)*7+kk][lane=q*16+(n&15)][8]
    if (tid < 28) {
        int kk = tid >> 2, q = tid & 3;
        s16x8 r;
#pragma unroll
        for (int j = 0; j < 8; ++j) r[j] = (short)pfsh[kk * 32 + q * 8 + j];
        size_t off = ((size_t)(n >> 4) * 7 + kk) * 64 + q * 16 + (n & 15);
        *reinterpret_cast<s16x8*>(&apf[off * 8]) = r;
    }

    const int par[NJ] = {0,0,0,0,1,2,3,4,5,6,7,8,9,9,9,12,13,14,16,17,18,19,20,21};
    if (tid < 12) {
        int r = tid >> 2, c = tid & 3;
        G[tid] = (c < 3) ? pose[(size_t)n * 216 + r * 3 + c] : Jl[r];
    }
    __syncthreads();
    for (int i = 1; i < NJ; ++i) {
        int p = par[i];
        if (tid < 12) {
            int r = tid >> 2, c = tid & 3;
            const float* gp = &G[p * 12 + r * 4];
            float v;
            if (c < 3) {
                const float* Ri = pose + (size_t)n * 216 + i * 9;
                v = gp[0] * Ri[0 * 3 + c] + gp[1] * Ri[1 * 3 + c] + gp[2] * Ri[2 * 3 + c];
            } else {
                float t0 = Jl[i * 3 + 0] - Jl[p * 3 + 0];
                float t1 = Jl[i * 3 + 1] - Jl[p * 3 + 1];
                float t2 = Jl[i * 3 + 2] - Jl[p * 3 + 2];
                v = gp[0] * t0 + gp[1] * t1 + gp[2] * t2 + gp[3];
            }
            G[i * 12 + tid] = v;
        }
        __syncthreads();
    }
    // an16[n][col(16)][k=j(32)]
    for (int e = tid; e < 512; e += 64) {
        int col = e >> 5, j = e & 31;
        float v = 0.f;
        if (col < 12 && j < NJ) {
            int r = col >> 2, c = col & 3;
            if (c < 3) v = G[j * 12 + r * 4 + c];
            else {
                const float* g = &G[j * 12 + r * 4];
                v = g[3] - (g[0] * Jl[j * 3 + 0] + g[1] * Jl[j * 3 + 1] + g[2] * Jl[j * 3 + 2]);
            }
        }
        an16[(size_t)n * 512 + e] = (_Float16)v;
    }
}

// ---------------------------------------------------------------------------
// k_gl: fused pose-GEMM + LBS (unchanged from R12).
__global__ __launch_bounds__(256) void k_gl(const unsigned short* __restrict__ apf,
                                            const unsigned short* __restrict__ bp,
                                            const float* __restrict__ vt,
                                            const float* __restrict__ ws,
                                            const _Float16* __restrict__ w16,
                                            const _Float16* __restrict__ an16,
                                            const float* __restrict__ trans,
                                            _Float16* __restrict__ vb) {
    int tid = threadIdx.x;
    int lane = tid & 63, w = tid >> 6;
    int m = lane & 15, q = lane >> 4;
    int cb = blockIdx.x;                 // 0..107  (64-v tile)
    int nb = blockIdx.y;                 // 0..7    (64-n tile)
    int nt = nb * 4 + w;

    __shared__ __align__(16) _Float16 sm[3][64][72];   // 27.6 KB posed verts
    __shared__ float smT[4][4][16][20];                // 20.5 KB T staging
    __shared__ float svt[192];
    __shared__ float ssc[64];
    __shared__ float strans[192];
    if (tid < 192) {
        int col = cb * 192 + tid;
        svt[tid] = (col < V3) ? vt[col] : 0.f;
        strans[tid] = trans[nb * 192 + tid];
    }
    if (tid < 64) ssc[tid] = ws[SCALE_OFF + nb * 64 + tid];

    // ---- stage 1: pose GEMM
    const unsigned short* abase = apf + (size_t)nt * 7 * 512 + lane * 8;
    const unsigned short* bbase = bp + (size_t)cb * 12 * 7 * 512 + lane * 8;

    f32x4 acc[12];
#pragma unroll
    for (int ct = 0; ct < 12; ++ct) acc[ct] = (f32x4){0.f, 0.f, 0.f, 0.f};

#pragma unroll
    for (int kk = 0; kk < 7; ++kk) {
        s16x8 a = *reinterpret_cast<const s16x8*>(abase + kk * 512);
#pragma unroll
        for (int ct = 0; ct < 12; ++ct) {
            s16x8 bfr = *reinterpret_cast<const s16x8*>(bbase + (ct * 7 + kk) * 512);
            acc[ct] = __builtin_amdgcn_mfma_f32_16x16x32_bf16(a, bfr, acc[ct], 0, 0, 0);
        }
    }
    __syncthreads();          // svt/ssc ready
#pragma unroll
    for (int ct = 0; ct < 12; ++ct) {
        int col_loc = ct * 16 + m;
        int v_loc = col_loc / 3;
        int c = col_loc - 3 * v_loc;
        float vtc = svt[col_loc];
#pragma unroll
        for (int r = 0; r < 4; ++r) {
            int n_loc = w * 16 + q * 4 + r;
            sm[c][n_loc][v_loc] = (_Float16)(acc[ct][r] + ssc[n_loc] * vtc);
        }
    }

    // ---- stage 2: LBS (T via MFMA, apply from LDS)
    h16x8 wf = *reinterpret_cast<const h16x8*>(
        &w16[(size_t)(cb * 64 + w * 16 + m) * 32 + q * 8]);
    int vloc = tid & 63, cc = tid >> 6;      // cc==3 idle in apply
    size_t vglob = (size_t)cb * 64 + vloc;
    __syncthreads();                          // sm complete

    for (int it = 0; it < 16; ++it) {
        int na = nb * 64 + it * 4;
#pragma unroll
        for (int which = 0; which < 4; ++which) {
            h16x8 bf = *reinterpret_cast<const h16x8*>(
                &an16[(size_t)(na + which) * 512 + m * 32 + q * 8]);
            f32x4 at = {0.f, 0.f, 0.f, 0.f};
            at = __builtin_amdgcn_mfma_f32_16x16x32_f16(wf, bf, at, 0, 0, 0);
#pragma unroll
            for (int r = 0; r < 4; ++r)
                smT[which][w][q * 4 + r][m] = at[r];
        }
        __syncthreads();
        if (cc < 3) {
#pragma unroll
            for (int which = 0; which < 4; ++which) {
                int nl = it * 4 + which;
                float4 T = *reinterpret_cast<const float4*>(
                    &smT[which][vloc >> 4][vloc & 15][cc * 4]);
                float px = (float)sm[0][nl][vloc];
                float py = (float)sm[1][nl][vloc];
                float pz = (float)sm[2][nl][vloc];
                float r = T.x * px + T.y * py + T.z * pz + T.w + strans[nl * 3 + cc];
                vb[(size_t)(nb * 64 + nl) * 3 * VP2 + (size_t)cc * VP2 + vglob] =
                    (_Float16)r;
            }
        }
        __syncthreads();
    }
}

// ---------------------------------------------------------------------------
// k_regm v4: grid (96 nc-tiles x 6 v-splits) = 576 blocks (~9 waves/CU).
// Each wave: 9 K-steps. LDS combine across 4 waves, atomicAdd partials.
__global__ __launch_bounds__(256) void k_regm(const _Float16* __restrict__ rb,
                                              const _Float16* __restrict__ vb,
                                              float* __restrict__ out) {
    int tid = threadIdx.x;
    int lane = tid & 63, w = tid >> 6;
    int m = lane & 15, q = lane >> 4;
    int nct = blockIdx.x;                    // 0..95
    int split = blockIdx.y;                  // 0..5

    const _Float16* brow = vb + (size_t)(nct * 16 + m) * VP2 + q * 8;
    const _Float16* abase = rb + (size_t)m * VP2 + q * 8;
    int vstart = (split * 4 + w) * 288;      // 9 steps of 32 per wave

    f32x4 acc[6];
#pragma unroll
    for (int kt = 0; kt < 6; ++kt) acc[kt] = (f32x4){0.f, 0.f, 0.f, 0.f};

#pragma unroll
    for (int s = 0; s < 9; ++s) {
        int off = vstart + s * 32;
        h16x8 b = *reinterpret_cast<const h16x8*>(brow + off);
#pragma unroll
        for (int kt = 0; kt < 6; ++kt) {
            h16x8 a = *reinterpret_cast<const h16x8*>(abase + (size_t)kt * 16 * VP2 + off);
            acc[kt] = __builtin_amdgcn_mfma_f32_16x16x32_f16(a, b, acc[kt], 0, 0, 0);
        }
    }
    __shared__ float sm[4][6][256];          // 24 KB
#pragma unroll
    for (int kt = 0; kt < 6; ++kt)
#pragma unroll
        for (int r = 0; r < 4; ++r)
            sm[w][kt][(q * 4 + r) * 16 + m] = acc[kt][r];
    __syncthreads();
    for (int e = tid; e < 6 * 256; e += 256) {
        int kt = e >> 8, i = e & 255;
        float s = sm[0][kt][i] + sm[1][kt][i] + sm[2][kt][i] + sm[3][kt][i];
        int k = kt * 16 + (i >> 4);
        int nc = nct * 16 + (i & 15);
        if (k < NK) {
            int n = nc / 3, c = nc - n * 3;
            atomicAdd(&out[(size_t)n * (NK * 3) + k * 3 + c], s);
        }
    }
}

// ---------------------------------------------------------------------------
extern "C" void kernel_launch(void* const* d_in, const int* in_sizes, int n_in,
                              void* d_out, int out_size, void* d_ws, size_t ws_size,
                              hipStream_t stream) {
    const float* pose  = (const float*)d_in[0];
    const float* betas = (const float*)d_in[1];
    const float* trans = (const float*)d_in[2];
    const float* vt    = (const float*)d_in[3];
    const float* sd    = (const float*)d_in[4];
    const float* jreg  = (const float*)d_in[5];
    const float* pdirs = (const float*)d_in[6];
    const float* lbsw  = (const float*)d_in[7];
    const float* b25   = (const float*)d_in[8];
    const float* face  = (const float*)d_in[9];
    float* ws  = (float*)d_ws;
    float* out = (float*)d_out;
    unsigned short* bf  = (unsigned short*)(ws + BF_OFF);
    unsigned short* apf = bf + APF_U;
    unsigned short* bp  = bf + BP_U;
    _Float16* rb  = (_Float16*)(bf + RB_U);
    _Float16* vb  = (_Float16*)(bf + VB_U);
    _Float16* w16 = (_Float16*)(ws + WT_OFF);
    _Float16* an16 = (_Float16*)(ws + AN_OFF);

    hipMemsetAsync(d_out, 0, (size_t)out_size * sizeof(float), stream);

    k_static<<<NB_STATIC, 256, 0, stream>>>(pdirs, sd, jreg, vt, lbsw, b25, face,
                                            bp, rb, w16, ws);
    k_head  <<<N, 64, 0, stream>>>(pose, betas, vt, sd, ws, apf, an16);
    k_gl    <<<dim3(108, 8), 256, 0, stream>>>(apf, bp, vt, ws, w16, an16, trans, vb);
    k_regm  <<<dim3(96, 6), 256, 0, stream>>>(rb, vb, out);
}